// Round 8
// baseline (188.148 us; speedup 1.0000x reference)
//
#include <hip/hip_runtime.h>
#include <hip/hip_fp16.h>

#define BOHR_F 0.5291772105638411f
#define HA_D   27.211386024367243
#define A1_F   0.4289f
#define A2_F   4.4407f
#define S6_F   1.0f
#define S8_F   0.7875f
#define KCN_F  16.0f
#define WF_F   4.0f
#define EPS_F  1.1920929e-07f

// sort-path fixed point: 15-bit fraction packed under 17-bit atom id
#define Q15_SCALE 32767.0f
#define Q15_INV   (1.0f/32767.0f)
// atomic-fallback fixed point
#define CN_SCALE 8388608.0f  // 2^23
#define CN_INV   (1.0f/8388608.0f)

#define NELEM  95
#define C6PADH 32            // 25 halfs -> 32 (64B row)
#define NBLK   512           // bin/scatter grid
#define BSW    512           // bin/scatter block

__device__ __forceinline__ float smooth_cutoff(float dr, float r_on, float r_cut) {
    float r_c = r_cut * r_cut;
    float r_o = r_on * r_on;
    float r   = dr * dr;
    float den = (r_c - r_o);
    float t   = r_c - r;
    float inner = (dr < r_cut)
        ? (t * t * (r_c + 2.0f * r - 3.0f * r_o)) / (den * den * den)
        : 0.0f;
    return (dr < r_on) ? 1.0f : inner;
}

__device__ __forceinline__ float edge_m(float dr, float rc) {
    if (!(dr > 0.0f)) return 0.0f;
    float count = 1.0f / (1.0f + expf(-KCN_F * (rc / dr - 1.0f)));
    return smooth_cutoff(dr, 20.0f, 25.0f) * count;
}

__device__ __forceinline__ void u2f2(unsigned u, float& a, float& b) {
    __half2 h = __builtin_bit_cast(__half2, u);
    float2 f = __half22float2(h);
    a = f.x; b = f.y;
}

// per-edge energy from fp16 atom records + fp16 c6 row
__device__ __forceinline__ float edge_e(float dr, uint4 Ri, uint4 Rj,
                                        uint4 c0, uint4 c1, uint4 c2, uint4 c3) {
    float wi[5], wj[5], qi, qj;
    u2f2(Ri.x, wi[0], wi[1]); u2f2(Ri.y, wi[2], wi[3]); u2f2(Ri.z, wi[4], qi);
    u2f2(Rj.x, wj[0], wj[1]); u2f2(Rj.y, wj[2], wj[3]); u2f2(Rj.z, wj[4], qj);
    float ct[26];
    u2f2(c0.x, ct[0],  ct[1]);  u2f2(c0.y, ct[2],  ct[3]);
    u2f2(c0.z, ct[4],  ct[5]);  u2f2(c0.w, ct[6],  ct[7]);
    u2f2(c1.x, ct[8],  ct[9]);  u2f2(c1.y, ct[10], ct[11]);
    u2f2(c1.z, ct[12], ct[13]); u2f2(c1.w, ct[14], ct[15]);
    u2f2(c2.x, ct[16], ct[17]); u2f2(c2.y, ct[18], ct[19]);
    u2f2(c2.z, ct[20], ct[21]); u2f2(c2.w, ct[22], ct[23]);
    u2f2(c3.x, ct[24], ct[25]);
    float c6 = 0.0f;
#pragma unroll
    for (int a = 0; a < 5; ++a)
#pragma unroll
        for (int b = 0; b < 5; ++b)
            c6 += wj[a] * wi[b] * ct[a * 5 + b];
    float qq = 3.0f * qi * qj;
    float rr = A1_F * sqrtf(qq) + A2_F;
    float dr2 = dr * dr;
    float dr6 = dr2 * dr2 * dr2;
    float dr8 = dr6 * dr2;
    float rr2 = rr * rr;
    float rr6 = rr2 * rr2 * rr2;
    float rr8 = rr6 * rr2;
    float damped = -c6 * (S6_F / (dr6 + rr6) + S8_F * qq / (dr8 + rr8));
    return smooth_cutoff(dr, 55.0f, 60.0f) * damped * 0.5f;
}

// ---------------- prep ----------------
__global__ __launch_bounds__(256)
void k_prep_c6(const float* __restrict__ src, __half* __restrict__ dst, int ntot) {
    int o = blockIdx.x * blockDim.x + threadIdx.x;
    if (o >= ntot) return;
    int p = o >> 5;
    int t = o & 31;
    dst[o] = __float2half((t < 25) ? src[p * 25 + t] : 0.0f);
}

// rcovZ[a] = {f32 rcov[numbers[a]], u32 numbers[a]}
__global__ __launch_bounds__(256)
void k_prep_atom(const int* __restrict__ numbers, const float* __restrict__ rcov,
                 uint2* __restrict__ rcovZ, int n_atoms) {
    int a = blockIdx.x * blockDim.x + threadIdx.x;
    if (a >= n_atoms) return;
    int Z = numbers[a];
    rcovZ[a] = make_uint2(__float_as_uint(rcov[Z]), (unsigned)Z);
}

// ---------------- sort path ----------------
// Pass A: packed2 = i<<15 | q15; zpair = Zj*95+Zi; per-block bucket hist.
template<bool STASH>
__global__ __launch_bounds__(BSW, 4)
void k_bin(const float* __restrict__ dr_vec,
           const int* __restrict__ idx_i, const int* __restrict__ idx_j,
           const uint2* __restrict__ rcovZ,
           unsigned* __restrict__ packed2,
           unsigned short* __restrict__ zpair,
           unsigned* __restrict__ ghist,
           float* __restrict__ dr_stash, int n_edges, int nb) {
    __shared__ unsigned hist[256];
    if (threadIdx.x < 256) hist[threadIdx.x] = 0;
    __syncthreads();
    int nquad = (n_edges + 3) >> 2;
    int stride = gridDim.x * blockDim.x;
    for (int qd = blockIdx.x * blockDim.x + threadIdx.x; qd < nquad; qd += stride) {
        int e0 = qd << 2;
        int ne = n_edges - e0; if (ne > 4) ne = 4;
        if (ne == 4) {
            float4 v0 = *reinterpret_cast<const float4*>(dr_vec + 3 * e0);
            float4 v1 = *reinterpret_cast<const float4*>(dr_vec + 3 * e0 + 4);
            float4 v2 = *reinterpret_cast<const float4*>(dr_vec + 3 * e0 + 8);
            float drq[4];
            drq[0] = sqrtf(v0.x*v0.x + v0.y*v0.y + v0.z*v0.z) / BOHR_F;
            drq[1] = sqrtf(v0.w*v0.w + v1.x*v1.x + v1.y*v1.y) / BOHR_F;
            drq[2] = sqrtf(v1.z*v1.z + v1.w*v1.w + v2.x*v2.x) / BOHR_F;
            drq[3] = sqrtf(v2.y*v2.y + v2.z*v2.z + v2.w*v2.w) / BOHR_F;
            int4 i4 = *reinterpret_cast<const int4*>(idx_i + e0);
            int4 j4 = *reinterpret_cast<const int4*>(idx_j + e0);
            int ia[4] = { i4.x, i4.y, i4.z, i4.w };
            int ja[4] = { j4.x, j4.y, j4.z, j4.w };
            uint2 RiZ[4], RjZ[4];
#pragma unroll
            for (int k = 0; k < 4; ++k) { RiZ[k] = rcovZ[ia[k]]; RjZ[k] = rcovZ[ja[k]]; }
            unsigned pk[4];
            unsigned short zz[4];
#pragma unroll
            for (int k = 0; k < 4; ++k) {
                float rc = __uint_as_float(RiZ[k].x) + __uint_as_float(RjZ[k].x);
                float m = edge_m(drq[k], rc);
                unsigned q = (unsigned)(m * Q15_SCALE + 0.5f);
                if (q > 0x7FFFu) q = 0x7FFFu;
                pk[k] = ((unsigned)ia[k] << 15) | q;
                zz[k] = (unsigned short)(RjZ[k].y * NELEM + RiZ[k].y);
                atomicAdd(&hist[ia[k] >> 9], 1u);
            }
            *reinterpret_cast<uint4*>(packed2 + e0) =
                make_uint4(pk[0], pk[1], pk[2], pk[3]);
            *reinterpret_cast<uint2*>(zpair + e0) =
                make_uint2((unsigned)zz[0] | ((unsigned)zz[1] << 16),
                           (unsigned)zz[2] | ((unsigned)zz[3] << 16));
            if (STASH)
                *reinterpret_cast<float4*>(dr_stash + e0) =
                    make_float4(drq[0], drq[1], drq[2], drq[3]);
        } else {
            for (int k = 0; k < ne; ++k) {
                int e = e0 + k;
                float x = dr_vec[3*e], y = dr_vec[3*e+1], z = dr_vec[3*e+2];
                float dr = sqrtf(x*x + y*y + z*z) / BOHR_F;
                if (STASH) dr_stash[e] = dr;
                int i = idx_i[e], j = idx_j[e];
                uint2 RiZ = rcovZ[i], RjZ = rcovZ[j];
                float m = edge_m(dr, __uint_as_float(RiZ.x) + __uint_as_float(RjZ.x));
                unsigned q = (unsigned)(m * Q15_SCALE + 0.5f);
                if (q > 0x7FFFu) q = 0x7FFFu;
                packed2[e] = ((unsigned)i << 15) | q;
                zpair[e] = (unsigned short)(RjZ.y * NELEM + RiZ.y);
                atomicAdd(&hist[i >> 9], 1u);
            }
        }
    }
    __syncthreads();
    if ((int)threadIdx.x < nb)
        ghist[(size_t)threadIdx.x * gridDim.x + blockIdx.x] = hist[threadIdx.x];
}

// Pass B1: per-bucket exclusive scan across NBLK block-counts; bucket totals.
__global__ __launch_bounds__(NBLK)
void k_scan_bucket(unsigned* __restrict__ ghist, unsigned* __restrict__ totals) {
    __shared__ unsigned s[NBLK];
    int b = blockIdx.x;
    int t = threadIdx.x;
    unsigned v = ghist[(size_t)b * NBLK + t];
    s[t] = v;
    __syncthreads();
    for (int off = 1; off < NBLK; off <<= 1) {
        unsigned x = (t >= off) ? s[t - off] : 0u;
        __syncthreads();
        s[t] += x;
        __syncthreads();
    }
    ghist[(size_t)b * NBLK + t] = s[t] - v;   // exclusive
    if (t == NBLK - 1) totals[b] = s[t];
}

// Pass B2: exclusive scan over bucket totals -> base[nb+1].
__global__ __launch_bounds__(256)
void k_scan_base(const unsigned* __restrict__ totals,
                 unsigned* __restrict__ base, int nb) {
    __shared__ unsigned s[256];
    int t = threadIdx.x;
    unsigned v = (t < nb) ? totals[t] : 0u;
    s[t] = v;
    __syncthreads();
    for (int off = 1; off < 256; off <<= 1) {
        unsigned x = (t >= off) ? s[t - off] : 0u;
        __syncthreads();
        s[t] += x;
        __syncthreads();
    }
    if (t < nb) base[t] = s[t] - v;
    if (t == 255) base[nb] = s[t];
}

// Pass C: scatter packed2 into bucket-sorted order (bucket = p>>24).
__global__ __launch_bounds__(BSW, 4)
void k_scatter(const unsigned* __restrict__ packed2,
               const unsigned* __restrict__ ghist,
               const unsigned* __restrict__ base,
               unsigned* __restrict__ pairs,
               int n_edges, int nb) {
    __shared__ unsigned ofs[256];
    if ((int)threadIdx.x < nb)
        ofs[threadIdx.x] = base[threadIdx.x]
                         + ghist[(size_t)threadIdx.x * gridDim.x + blockIdx.x];
    __syncthreads();
    int nquad = (n_edges + 3) >> 2;
    int stride = gridDim.x * blockDim.x;
    for (int qd = blockIdx.x * blockDim.x + threadIdx.x; qd < nquad; qd += stride) {
        int e0 = qd << 2;
        int ne = n_edges - e0; if (ne > 4) ne = 4;
        if (ne == 4) {
            uint4 p4 = *reinterpret_cast<const uint4*>(packed2 + e0);
            unsigned pk[4] = { p4.x, p4.y, p4.z, p4.w };
#pragma unroll
            for (int k = 0; k < 4; ++k) {
                unsigned pos = atomicAdd(&ofs[pk[k] >> 24], 1u);
                pairs[pos] = pk[k];
            }
        } else {
            for (int k = 0; k < ne; ++k) {
                unsigned p = packed2[e0 + k];
                unsigned pos = atomicAdd(&ofs[p >> 24], 1u);
                pairs[pos] = p;
            }
        }
    }
}

// Pass D: per-bucket LDS reduce -> cn; fused weights -> rec {w0..4, r4r2, 0, 0}
__global__ __launch_bounds__(512)
void k_reduce_weights(const unsigned* __restrict__ pairs,
                      const unsigned* __restrict__ base,
                      const int* __restrict__ numbers,
                      const float* __restrict__ ref_cn_table,
                      const float* __restrict__ r4r2,
                      __half* __restrict__ rec,
                      int n_atoms) {
    __shared__ unsigned hist[512];
    hist[threadIdx.x] = 0;
    __syncthreads();
    int b = blockIdx.x;
    unsigned start = base[b];
    unsigned end   = base[b + 1];
    for (unsigned k = start + threadIdx.x; k < end; k += 512) {
        unsigned p = pairs[k];
        atomicAdd(&hist[(p >> 15) & 511], p & 0x7FFFu);
    }
    __syncthreads();
    int a = (b << 9) + threadIdx.x;
    if (a < n_atoms) {
        float c = (float)hist[threadIdx.x] * Q15_INV;
        int Z = numbers[a];
        float w[5];
        float s = 0.0f;
#pragma unroll
        for (int r = 0; r < 5; ++r) {
            float rcn = ref_cn_table[Z * 5 + r];
            float d = rcn - c;
            float wv = (rcn >= 0.0f) ? expf(-WF_F * d * d) : 0.0f;
            w[r] = wv;
            s += wv;
        }
        float den = s + EPS_F;
        __half* rr = rec + (size_t)a * 8;
#pragma unroll
        for (int r = 0; r < 5; ++r) rr[r] = __float2half(w[r] / den);
        rr[5] = __float2half(r4r2[Z]);
        rr[6] = __float2half(0.0f);
        rr[7] = __float2half(0.0f);
    }
}

// ---------------- atomic fallback path ----------------
template<bool STASH>
__global__ __launch_bounds__(256)
void k_edges_cn_atomic(const float* __restrict__ dr_vec,
                       const int* __restrict__ idx_i,
                       const int* __restrict__ idx_j,
                       const uint2* __restrict__ rcovZ,
                       unsigned* __restrict__ cn_u32,
                       unsigned short* __restrict__ zpair,
                       float* __restrict__ dr_stash,
                       int n_edges) {
    int e = blockIdx.x * blockDim.x + threadIdx.x;
    if (e >= n_edges) return;
    float x = dr_vec[3 * e + 0];
    float y = dr_vec[3 * e + 1];
    float z = dr_vec[3 * e + 2];
    float dr = sqrtf(x * x + y * y + z * z) / BOHR_F;
    if (STASH) dr_stash[e] = dr;
    int i = idx_i[e];
    int j = idx_j[e];
    uint2 RiZ = rcovZ[i], RjZ = rcovZ[j];
    zpair[e] = (unsigned short)(RjZ.y * NELEM + RiZ.y);
    float m = edge_m(dr, __uint_as_float(RiZ.x) + __uint_as_float(RjZ.x));
    unsigned q = (unsigned)(m * CN_SCALE + 0.5f);
    if (q) atomicAdd(&cn_u32[i], q);
}

__global__ __launch_bounds__(256)
void k_atom_weights_rec(const unsigned* __restrict__ cn_u32,
                        const int* __restrict__ numbers,
                        const float* __restrict__ ref_cn_table,
                        const float* __restrict__ r4r2,
                        __half* __restrict__ rec,
                        int n_atoms) {
    int a = blockIdx.x * blockDim.x + threadIdx.x;
    if (a >= n_atoms) return;
    float c = (float)cn_u32[a] * CN_INV;
    int Z = numbers[a];
    float w[5];
    float s = 0.0f;
#pragma unroll
    for (int r = 0; r < 5; ++r) {
        float rcn = ref_cn_table[Z * 5 + r];
        float d = rcn - c;
        float wv = (rcn >= 0.0f) ? expf(-WF_F * d * d) : 0.0f;
        w[r] = wv;
        s += wv;
    }
    float den = s + EPS_F;
    __half* rr = rec + (size_t)a * 8;
#pragma unroll
    for (int r = 0; r < 5; ++r) rr[r] = __float2half(w[r] / den);
    rr[5] = __float2half(r4r2[Z]);
    rr[6] = __float2half(0.0f);
    rr[7] = __float2half(0.0f);
}

// ---------------- energy ----------------
// 8 edges/thread, depth-1 gather chains, 2-stage software pipeline.
template<bool STASH>
__global__ __launch_bounds__(256, 4)
void k_energy(const float* __restrict__ dr_vec,
              const float* __restrict__ dr_stash,
              const int* __restrict__ idx_i,
              const int* __restrict__ idx_j,
              const unsigned short* __restrict__ zpair,
              const __half* __restrict__ rec,    // [N,8] halfs
              const __half* __restrict__ c6h,    // [95*95][32] halfs
              double* __restrict__ e_acc,
              int n_edges) {
    double local = 0.0;
    int noct = (n_edges + 7) >> 3;
    int tid = blockIdx.x * blockDim.x + threadIdx.x;
    int stride = gridDim.x * blockDim.x;
    for (int oc = tid; oc < noct; oc += stride) {
        int e0 = oc << 3;
        int ne = n_edges - e0;
        if (ne > 8) ne = 8;
        if (ne == 8) {
            int4 iA = *reinterpret_cast<const int4*>(idx_i + e0);
            int4 iB = *reinterpret_cast<const int4*>(idx_i + e0 + 4);
            int4 jA = *reinterpret_cast<const int4*>(idx_j + e0);
            int4 jB = *reinterpret_cast<const int4*>(idx_j + e0 + 4);
            int ia[8] = { iA.x, iA.y, iA.z, iA.w, iB.x, iB.y, iB.z, iB.w };
            int ja[8] = { jA.x, jA.y, jA.z, jA.w, jB.x, jB.y, jB.z, jB.w };
            uint4 z4 = *reinterpret_cast<const uint4*>(zpair + e0);
            int zp[8] = { (int)(z4.x & 0xFFFFu), (int)(z4.x >> 16),
                          (int)(z4.y & 0xFFFFu), (int)(z4.y >> 16),
                          (int)(z4.z & 0xFFFFu), (int)(z4.z >> 16),
                          (int)(z4.w & 0xFFFFu), (int)(z4.w >> 16) };
            float drq[8];
            if (STASH) {
                float4 dA = *reinterpret_cast<const float4*>(dr_stash + e0);
                float4 dB = *reinterpret_cast<const float4*>(dr_stash + e0 + 4);
                drq[0]=dA.x; drq[1]=dA.y; drq[2]=dA.z; drq[3]=dA.w;
                drq[4]=dB.x; drq[5]=dB.y; drq[6]=dB.z; drq[7]=dB.w;
            } else {
                const float4* dv = reinterpret_cast<const float4*>(dr_vec + 3 * e0);
                float4 v0=dv[0], v1=dv[1], v2=dv[2], v3=dv[3], v4=dv[4], v5=dv[5];
                drq[0]=sqrtf(v0.x*v0.x+v0.y*v0.y+v0.z*v0.z)/BOHR_F;
                drq[1]=sqrtf(v0.w*v0.w+v1.x*v1.x+v1.y*v1.y)/BOHR_F;
                drq[2]=sqrtf(v1.z*v1.z+v1.w*v1.w+v2.x*v2.x)/BOHR_F;
                drq[3]=sqrtf(v2.y*v2.y+v2.z*v2.z+v2.w*v2.w)/BOHR_F;
                drq[4]=sqrtf(v3.x*v3.x+v3.y*v3.y+v3.z*v3.z)/BOHR_F;
                drq[5]=sqrtf(v3.w*v3.w+v4.x*v4.x+v4.y*v4.y)/BOHR_F;
                drq[6]=sqrtf(v4.z*v4.z+v4.w*v4.w+v5.x*v5.x)/BOHR_F;
                drq[7]=sqrtf(v5.y*v5.y+v5.z*v5.z+v5.w*v5.w)/BOHR_F;
            }
            // 2-stage pipeline: loads for k+1 in flight while computing k
            uint4 Ri[2], Rj[2], C0[2], C1[2], C2[2], C3[2];
            Ri[0] = *reinterpret_cast<const uint4*>(rec + (size_t)ia[0] * 8);
            Rj[0] = *reinterpret_cast<const uint4*>(rec + (size_t)ja[0] * 8);
            {
                const uint4* cp = reinterpret_cast<const uint4*>(
                    c6h + (size_t)zp[0] * C6PADH);
                C0[0]=cp[0]; C1[0]=cp[1]; C2[0]=cp[2]; C3[0]=cp[3];
            }
#pragma unroll
            for (int k = 0; k < 8; ++k) {
                const int cur = k & 1, nxt = cur ^ 1;
                if (k < 7) {
                    Ri[nxt] = *reinterpret_cast<const uint4*>(rec + (size_t)ia[k+1] * 8);
                    Rj[nxt] = *reinterpret_cast<const uint4*>(rec + (size_t)ja[k+1] * 8);
                    const uint4* cp = reinterpret_cast<const uint4*>(
                        c6h + (size_t)zp[k+1] * C6PADH);
                    C0[nxt]=cp[0]; C1[nxt]=cp[1]; C2[nxt]=cp[2]; C3[nxt]=cp[3];
                }
                local += (double)edge_e(drq[k], Ri[cur], Rj[cur],
                                        C0[cur], C1[cur], C2[cur], C3[cur]);
            }
        } else {
            for (int k = 0; k < ne; ++k) {
                int e = e0 + k;
                float dr;
                if (STASH) dr = dr_stash[e];
                else {
                    float x = dr_vec[3*e], y = dr_vec[3*e+1], z = dr_vec[3*e+2];
                    dr = sqrtf(x*x + y*y + z*z) / BOHR_F;
                }
                int i = idx_i[e], j = idx_j[e];
                uint4 Ri = *reinterpret_cast<const uint4*>(rec + (size_t)i * 8);
                uint4 Rj = *reinterpret_cast<const uint4*>(rec + (size_t)j * 8);
                const uint4* cp = reinterpret_cast<const uint4*>(
                    c6h + (size_t)zpair[e] * C6PADH);
                local += (double)edge_e(dr, Ri, Rj, cp[0], cp[1], cp[2], cp[3]);
            }
        }
    }

    __shared__ double sdata[4];
    for (int off = 32; off > 0; off >>= 1)
        local += __shfl_down(local, off, 64);
    int lane = threadIdx.x & 63;
    int wid  = threadIdx.x >> 6;
    if (lane == 0) sdata[wid] = local;
    __syncthreads();
    if (threadIdx.x == 0) {
        double s = sdata[0] + sdata[1] + sdata[2] + sdata[3];
        atomicAdd(e_acc, s);
    }
}

__global__ void k_finalize(const double* __restrict__ e_acc,
                           float* __restrict__ out) {
    out[0] = (float)(e_acc[0] * HA_D);
}

static inline size_t a16(size_t x) { return (x + 15) & ~(size_t)15; }

extern "C" void kernel_launch(void* const* d_in, const int* in_sizes, int n_in,
                              void* d_out, int out_size, void* d_ws, size_t ws_size,
                              hipStream_t stream) {
    const float* dr_vec      = (const float*)d_in[0];
    const float* ref_cn_tab  = (const float*)d_in[1];
    const float* ref_c6_tab  = (const float*)d_in[2];
    const float* r4r2        = (const float*)d_in[3];
    const float* rcov        = (const float*)d_in[4];
    const int*   numbers     = (const int*)d_in[5];
    const int*   idx         = (const int*)d_in[6];

    int n_atoms = in_sizes[5];
    int n_edges = in_sizes[6] / 2;
    const int* idx_i = idx;
    const int* idx_j = idx + n_edges;

    const int BS = 256;
    int nb = (n_atoms + 511) >> 9;
    int c6tot = NELEM * NELEM * C6PADH;

    char* ws = (char*)d_ws;
    double* e_acc = (double*)ws;

    // common prefix: [e_acc 16][rec N*16B][c6h][rcovZ N*8]
    size_t off_rec = 16;
    size_t off_c6p = a16(off_rec + (size_t)n_atoms * 8 * 2);
    size_t off_rcZ = a16(off_c6p + (size_t)c6tot * 2);
    size_t off_var = a16(off_rcZ + (size_t)n_atoms * 8);

    // sort path: [packed2 E*4][zpair E*2][pairs E*4][ghist][tot][base][stash E*4]
    size_t off_packed = off_var;
    size_t off_zp     = a16(off_packed + (size_t)n_edges * 4);
    size_t off_pairs  = a16(off_zp + (size_t)n_edges * 2);
    size_t off_ghist  = a16(off_pairs + (size_t)n_edges * 4);
    size_t off_tot    = a16(off_ghist + (size_t)nb * NBLK * 4);
    size_t off_base   = a16(off_tot + (size_t)nb * 4);
    size_t off_stash  = a16(off_base + (size_t)(nb + 1) * 4);
    size_t need_sort       = off_stash;
    size_t need_sort_stash = off_stash + (size_t)n_edges * 4;

    // atomic path: [cn N*4][zpair E*2][stash E*4]
    size_t off_cn   = off_var;
    size_t off_zpa  = a16(off_cn + (size_t)n_atoms * 4);
    size_t off_st_a = a16(off_zpa + (size_t)n_edges * 2);
    size_t need_atomic_stash = off_st_a + (size_t)n_edges * 4;

    int noct    = (n_edges + 7) >> 3;
    int grid_o  = (noct + BS - 1) / BS;
    if (grid_o > 8192) grid_o = 8192;
    int grid_c6 = (c6tot + BS - 1) / BS;
    int grid_a  = (n_atoms + BS - 1) / BS;

    __half* rec   = (__half*)(ws + off_rec);
    __half* c6h   = (__half*)(ws + off_c6p);
    uint2*  rcovZ = (uint2*)(ws + off_rcZ);

    k_prep_c6<<<grid_c6, BS, 0, stream>>>(ref_c6_tab, c6h, c6tot);
    k_prep_atom<<<grid_a, BS, 0, stream>>>(numbers, rcov, rcovZ, n_atoms);

    if (n_atoms <= (1 << 17) && nb <= 256 && ws_size >= need_sort) {
        bool stash = (ws_size >= need_sort_stash);
        unsigned*       packed2 = (unsigned*)(ws + off_packed);
        unsigned short* zpair   = (unsigned short*)(ws + off_zp);
        unsigned*       pairs   = (unsigned*)(ws + off_pairs);
        unsigned*       ghist   = (unsigned*)(ws + off_ghist);
        unsigned*       totals  = (unsigned*)(ws + off_tot);
        unsigned*       base    = (unsigned*)(ws + off_base);
        float* dr_stash = stash ? (float*)(ws + off_stash) : nullptr;

        hipMemsetAsync(d_ws, 0, 16, stream);   // e_acc only

        if (stash)
            k_bin<true><<<NBLK, BSW, 0, stream>>>(dr_vec, idx_i, idx_j, rcovZ,
                packed2, zpair, ghist, dr_stash, n_edges, nb);
        else
            k_bin<false><<<NBLK, BSW, 0, stream>>>(dr_vec, idx_i, idx_j, rcovZ,
                packed2, zpair, ghist, nullptr, n_edges, nb);

        k_scan_bucket<<<nb, NBLK, 0, stream>>>(ghist, totals);
        k_scan_base<<<1, 256, 0, stream>>>(totals, base, nb);

        k_scatter<<<NBLK, BSW, 0, stream>>>(packed2, ghist, base, pairs,
                                            n_edges, nb);

        k_reduce_weights<<<nb, 512, 0, stream>>>(pairs, base, numbers,
            ref_cn_tab, r4r2, rec, n_atoms);

        if (stash)
            k_energy<true><<<grid_o, BS, 0, stream>>>(dr_vec, dr_stash, idx_i,
                idx_j, zpair, rec, c6h, e_acc, n_edges);
        else
            k_energy<false><<<grid_o, BS, 0, stream>>>(dr_vec, nullptr, idx_i,
                idx_j, zpair, rec, c6h, e_acc, n_edges);
    } else {
        bool stash = (ws_size >= need_atomic_stash);
        unsigned*       cn_u32 = (unsigned*)(ws + off_cn);
        unsigned short* zpair  = (unsigned short*)(ws + off_zpa);
        float* dr_stash = stash ? (float*)(ws + off_st_a) : nullptr;

        hipMemsetAsync(d_ws, 0, 16, stream);
        hipMemsetAsync(cn_u32, 0, (size_t)n_atoms * 4, stream);

        int grid_e = (n_edges + BS - 1) / BS;

        if (stash)
            k_edges_cn_atomic<true><<<grid_e, BS, 0, stream>>>(dr_vec, idx_i,
                idx_j, rcovZ, cn_u32, zpair, dr_stash, n_edges);
        else
            k_edges_cn_atomic<false><<<grid_e, BS, 0, stream>>>(dr_vec, idx_i,
                idx_j, rcovZ, cn_u32, zpair, nullptr, n_edges);

        k_atom_weights_rec<<<grid_a, BS, 0, stream>>>(cn_u32, numbers,
            ref_cn_tab, r4r2, rec, n_atoms);

        if (stash)
            k_energy<true><<<grid_o, BS, 0, stream>>>(dr_vec, dr_stash, idx_i,
                idx_j, zpair, rec, c6h, e_acc, n_edges);
        else
            k_energy<false><<<grid_o, BS, 0, stream>>>(dr_vec, nullptr, idx_i,
                idx_j, zpair, rec, c6h, e_acc, n_edges);
    }

    k_finalize<<<1, 1, 0, stream>>>(e_acc, (float*)d_out);
}

// Round 9
// 184.947 us; speedup vs baseline: 1.0173x; 1.0173x over previous
//
#include <hip/hip_runtime.h>
#include <hip/hip_fp16.h>

#define BOHR_F 0.5291772105638411f
#define HA_D   27.211386024367243
#define A1_F   0.4289f
#define A2_F   4.4407f
#define S6_F   1.0f
#define S8_F   0.7875f
#define KCN_F  16.0f
#define WF_F   4.0f
#define EPS_F  1.1920929e-07f

// sort-path fixed point: 15-bit fraction packed under 17-bit atom id
#define Q15_SCALE 32767.0f
#define Q15_INV   (1.0f/32767.0f)
// atomic-fallback fixed point
#define CN_SCALE 8388608.0f  // 2^23
#define CN_INV   (1.0f/8388608.0f)

#define NELEM  95
#define C6PADH 32            // 25 halfs -> 32 (64B row)
#define NBLK   512           // bin/scatter grid
#define BSW    512           // bin/scatter block

__device__ __forceinline__ float smooth_cutoff(float dr, float r_on, float r_cut) {
    float r_c = r_cut * r_cut;
    float r_o = r_on * r_on;
    float r   = dr * dr;
    float den = (r_c - r_o);
    float t   = r_c - r;
    float inner = (dr < r_cut)
        ? (t * t * (r_c + 2.0f * r - 3.0f * r_o)) / (den * den * den)
        : 0.0f;
    return (dr < r_on) ? 1.0f : inner;
}

__device__ __forceinline__ float edge_m(float dr, float rc) {
    if (!(dr > 0.0f)) return 0.0f;
    float count = 1.0f / (1.0f + expf(-KCN_F * (rc / dr - 1.0f)));
    return smooth_cutoff(dr, 20.0f, 25.0f) * count;
}

__device__ __forceinline__ void u2f2(unsigned u, float& a, float& b) {
    __half2 h = __builtin_bit_cast(__half2, u);
    float2 f = __half22float2(h);
    a = f.x; b = f.y;
}

// per-edge energy from fp16 atom records + fp16 c6 row
__device__ __forceinline__ float edge_e(float dr, uint4 Ri, uint4 Rj,
                                        uint4 c0, uint4 c1, uint4 c2, uint4 c3) {
    float wi[5], wj[5], qi, qj;
    u2f2(Ri.x, wi[0], wi[1]); u2f2(Ri.y, wi[2], wi[3]); u2f2(Ri.z, wi[4], qi);
    u2f2(Rj.x, wj[0], wj[1]); u2f2(Rj.y, wj[2], wj[3]); u2f2(Rj.z, wj[4], qj);
    float ct[26];
    u2f2(c0.x, ct[0],  ct[1]);  u2f2(c0.y, ct[2],  ct[3]);
    u2f2(c0.z, ct[4],  ct[5]);  u2f2(c0.w, ct[6],  ct[7]);
    u2f2(c1.x, ct[8],  ct[9]);  u2f2(c1.y, ct[10], ct[11]);
    u2f2(c1.z, ct[12], ct[13]); u2f2(c1.w, ct[14], ct[15]);
    u2f2(c2.x, ct[16], ct[17]); u2f2(c2.y, ct[18], ct[19]);
    u2f2(c2.z, ct[20], ct[21]); u2f2(c2.w, ct[22], ct[23]);
    u2f2(c3.x, ct[24], ct[25]);
    float c6 = 0.0f;
#pragma unroll
    for (int a = 0; a < 5; ++a)
#pragma unroll
        for (int b = 0; b < 5; ++b)
            c6 += wj[a] * wi[b] * ct[a * 5 + b];
    float qq = 3.0f * qi * qj;
    float rr = A1_F * sqrtf(qq) + A2_F;
    float dr2 = dr * dr;
    float dr6 = dr2 * dr2 * dr2;
    float dr8 = dr6 * dr2;
    float rr2 = rr * rr;
    float rr6 = rr2 * rr2 * rr2;
    float rr8 = rr6 * rr2;
    float damped = -c6 * (S6_F / (dr6 + rr6) + S8_F * qq / (dr8 + rr8));
    return smooth_cutoff(dr, 55.0f, 60.0f) * damped * 0.5f;
}

// ---------------- prep ----------------
__global__ __launch_bounds__(256)
void k_prep_c6(const float* __restrict__ src, __half* __restrict__ dst, int ntot) {
    int o = blockIdx.x * blockDim.x + threadIdx.x;
    if (o >= ntot) return;
    int p = o >> 5;
    int t = o & 31;
    dst[o] = __float2half((t < 25) ? src[p * 25 + t] : 0.0f);
}

// rcovZ[a] = {f32 rcov[numbers[a]], u32 numbers[a]}
__global__ __launch_bounds__(256)
void k_prep_atom(const int* __restrict__ numbers, const float* __restrict__ rcov,
                 uint2* __restrict__ rcovZ, int n_atoms) {
    int a = blockIdx.x * blockDim.x + threadIdx.x;
    if (a >= n_atoms) return;
    int Z = numbers[a];
    rcovZ[a] = make_uint2(__float_as_uint(rcov[Z]), (unsigned)Z);
}

// ---------------- sort path ----------------
// Pass A: packed2 = i<<15 | q15; zpair = Zj*95+Zi; per-block bucket hist.
template<bool STASH>
__global__ __launch_bounds__(BSW, 4)
void k_bin(const float* __restrict__ dr_vec,
           const int* __restrict__ idx_i, const int* __restrict__ idx_j,
           const uint2* __restrict__ rcovZ,
           unsigned* __restrict__ packed2,
           unsigned short* __restrict__ zpair,
           unsigned* __restrict__ ghist,
           float* __restrict__ dr_stash, int n_edges, int nb) {
    __shared__ unsigned hist[256];
    if (threadIdx.x < 256) hist[threadIdx.x] = 0;
    __syncthreads();
    int nquad = (n_edges + 3) >> 2;
    int stride = gridDim.x * blockDim.x;
    for (int qd = blockIdx.x * blockDim.x + threadIdx.x; qd < nquad; qd += stride) {
        int e0 = qd << 2;
        int ne = n_edges - e0; if (ne > 4) ne = 4;
        if (ne == 4) {
            float4 v0 = *reinterpret_cast<const float4*>(dr_vec + 3 * e0);
            float4 v1 = *reinterpret_cast<const float4*>(dr_vec + 3 * e0 + 4);
            float4 v2 = *reinterpret_cast<const float4*>(dr_vec + 3 * e0 + 8);
            float drq[4];
            drq[0] = sqrtf(v0.x*v0.x + v0.y*v0.y + v0.z*v0.z) / BOHR_F;
            drq[1] = sqrtf(v0.w*v0.w + v1.x*v1.x + v1.y*v1.y) / BOHR_F;
            drq[2] = sqrtf(v1.z*v1.z + v1.w*v1.w + v2.x*v2.x) / BOHR_F;
            drq[3] = sqrtf(v2.y*v2.y + v2.z*v2.z + v2.w*v2.w) / BOHR_F;
            int4 i4 = *reinterpret_cast<const int4*>(idx_i + e0);
            int4 j4 = *reinterpret_cast<const int4*>(idx_j + e0);
            int ia[4] = { i4.x, i4.y, i4.z, i4.w };
            int ja[4] = { j4.x, j4.y, j4.z, j4.w };
            uint2 RiZ[4], RjZ[4];
#pragma unroll
            for (int k = 0; k < 4; ++k) { RiZ[k] = rcovZ[ia[k]]; RjZ[k] = rcovZ[ja[k]]; }
            unsigned pk[4];
            unsigned short zz[4];
#pragma unroll
            for (int k = 0; k < 4; ++k) {
                float rc = __uint_as_float(RiZ[k].x) + __uint_as_float(RjZ[k].x);
                float m = edge_m(drq[k], rc);
                unsigned q = (unsigned)(m * Q15_SCALE + 0.5f);
                if (q > 0x7FFFu) q = 0x7FFFu;
                pk[k] = ((unsigned)ia[k] << 15) | q;
                zz[k] = (unsigned short)(RjZ[k].y * NELEM + RiZ[k].y);
                atomicAdd(&hist[ia[k] >> 9], 1u);
            }
            *reinterpret_cast<uint4*>(packed2 + e0) =
                make_uint4(pk[0], pk[1], pk[2], pk[3]);
            *reinterpret_cast<uint2*>(zpair + e0) =
                make_uint2((unsigned)zz[0] | ((unsigned)zz[1] << 16),
                           (unsigned)zz[2] | ((unsigned)zz[3] << 16));
            if (STASH)
                *reinterpret_cast<float4*>(dr_stash + e0) =
                    make_float4(drq[0], drq[1], drq[2], drq[3]);
        } else {
            for (int k = 0; k < ne; ++k) {
                int e = e0 + k;
                float x = dr_vec[3*e], y = dr_vec[3*e+1], z = dr_vec[3*e+2];
                float dr = sqrtf(x*x + y*y + z*z) / BOHR_F;
                if (STASH) dr_stash[e] = dr;
                int i = idx_i[e], j = idx_j[e];
                uint2 RiZ = rcovZ[i], RjZ = rcovZ[j];
                float m = edge_m(dr, __uint_as_float(RiZ.x) + __uint_as_float(RjZ.x));
                unsigned q = (unsigned)(m * Q15_SCALE + 0.5f);
                if (q > 0x7FFFu) q = 0x7FFFu;
                packed2[e] = ((unsigned)i << 15) | q;
                zpair[e] = (unsigned short)(RjZ.y * NELEM + RiZ.y);
                atomicAdd(&hist[i >> 9], 1u);
            }
        }
    }
    __syncthreads();
    if ((int)threadIdx.x < nb)
        ghist[(size_t)threadIdx.x * gridDim.x + blockIdx.x] = hist[threadIdx.x];
}

// Pass B1: per-bucket exclusive scan across NBLK block-counts; bucket totals.
__global__ __launch_bounds__(NBLK)
void k_scan_bucket(unsigned* __restrict__ ghist, unsigned* __restrict__ totals) {
    __shared__ unsigned s[NBLK];
    int b = blockIdx.x;
    int t = threadIdx.x;
    unsigned v = ghist[(size_t)b * NBLK + t];
    s[t] = v;
    __syncthreads();
    for (int off = 1; off < NBLK; off <<= 1) {
        unsigned x = (t >= off) ? s[t - off] : 0u;
        __syncthreads();
        s[t] += x;
        __syncthreads();
    }
    ghist[(size_t)b * NBLK + t] = s[t] - v;   // exclusive
    if (t == NBLK - 1) totals[b] = s[t];
}

// Pass B2: exclusive scan over bucket totals -> base[nb+1].
__global__ __launch_bounds__(256)
void k_scan_base(const unsigned* __restrict__ totals,
                 unsigned* __restrict__ base, int nb) {
    __shared__ unsigned s[256];
    int t = threadIdx.x;
    unsigned v = (t < nb) ? totals[t] : 0u;
    s[t] = v;
    __syncthreads();
    for (int off = 1; off < 256; off <<= 1) {
        unsigned x = (t >= off) ? s[t - off] : 0u;
        __syncthreads();
        s[t] += x;
        __syncthreads();
    }
    if (t < nb) base[t] = s[t] - v;
    if (t == 255) base[nb] = s[t];
}

// Pass C: scatter packed2 into bucket-sorted order (bucket = p>>24).
__global__ __launch_bounds__(BSW, 4)
void k_scatter(const unsigned* __restrict__ packed2,
               const unsigned* __restrict__ ghist,
               const unsigned* __restrict__ base,
               unsigned* __restrict__ pairs,
               int n_edges, int nb) {
    __shared__ unsigned ofs[256];
    if ((int)threadIdx.x < nb)
        ofs[threadIdx.x] = base[threadIdx.x]
                         + ghist[(size_t)threadIdx.x * gridDim.x + blockIdx.x];
    __syncthreads();
    int nquad = (n_edges + 3) >> 2;
    int stride = gridDim.x * blockDim.x;
    for (int qd = blockIdx.x * blockDim.x + threadIdx.x; qd < nquad; qd += stride) {
        int e0 = qd << 2;
        int ne = n_edges - e0; if (ne > 4) ne = 4;
        if (ne == 4) {
            uint4 p4 = *reinterpret_cast<const uint4*>(packed2 + e0);
            unsigned pk[4] = { p4.x, p4.y, p4.z, p4.w };
#pragma unroll
            for (int k = 0; k < 4; ++k) {
                unsigned pos = atomicAdd(&ofs[pk[k] >> 24], 1u);
                pairs[pos] = pk[k];
            }
        } else {
            for (int k = 0; k < ne; ++k) {
                unsigned p = packed2[e0 + k];
                unsigned pos = atomicAdd(&ofs[p >> 24], 1u);
                pairs[pos] = p;
            }
        }
    }
}

// Pass D: per-bucket LDS reduce -> cn; fused weights -> rec {w0..4, r4r2, 0, 0}
__global__ __launch_bounds__(512)
void k_reduce_weights(const unsigned* __restrict__ pairs,
                      const unsigned* __restrict__ base,
                      const int* __restrict__ numbers,
                      const float* __restrict__ ref_cn_table,
                      const float* __restrict__ r4r2,
                      __half* __restrict__ rec,
                      int n_atoms) {
    __shared__ unsigned hist[512];
    hist[threadIdx.x] = 0;
    __syncthreads();
    int b = blockIdx.x;
    unsigned start = base[b];
    unsigned end   = base[b + 1];
    for (unsigned k = start + threadIdx.x; k < end; k += 512) {
        unsigned p = pairs[k];
        atomicAdd(&hist[(p >> 15) & 511], p & 0x7FFFu);
    }
    __syncthreads();
    int a = (b << 9) + threadIdx.x;
    if (a < n_atoms) {
        float c = (float)hist[threadIdx.x] * Q15_INV;
        int Z = numbers[a];
        float w[5];
        float s = 0.0f;
#pragma unroll
        for (int r = 0; r < 5; ++r) {
            float rcn = ref_cn_table[Z * 5 + r];
            float d = rcn - c;
            float wv = (rcn >= 0.0f) ? expf(-WF_F * d * d) : 0.0f;
            w[r] = wv;
            s += wv;
        }
        float den = s + EPS_F;
        __half* rr = rec + (size_t)a * 8;
#pragma unroll
        for (int r = 0; r < 5; ++r) rr[r] = __float2half(w[r] / den);
        rr[5] = __float2half(r4r2[Z]);
        rr[6] = __float2half(0.0f);
        rr[7] = __float2half(0.0f);
    }
}

// ---------------- atomic fallback path ----------------
template<bool STASH>
__global__ __launch_bounds__(256)
void k_edges_cn_atomic(const float* __restrict__ dr_vec,
                       const int* __restrict__ idx_i,
                       const int* __restrict__ idx_j,
                       const uint2* __restrict__ rcovZ,
                       unsigned* __restrict__ cn_u32,
                       unsigned short* __restrict__ zpair,
                       float* __restrict__ dr_stash,
                       int n_edges) {
    int e = blockIdx.x * blockDim.x + threadIdx.x;
    if (e >= n_edges) return;
    float x = dr_vec[3 * e + 0];
    float y = dr_vec[3 * e + 1];
    float z = dr_vec[3 * e + 2];
    float dr = sqrtf(x * x + y * y + z * z) / BOHR_F;
    if (STASH) dr_stash[e] = dr;
    int i = idx_i[e];
    int j = idx_j[e];
    uint2 RiZ = rcovZ[i], RjZ = rcovZ[j];
    zpair[e] = (unsigned short)(RjZ.y * NELEM + RiZ.y);
    float m = edge_m(dr, __uint_as_float(RiZ.x) + __uint_as_float(RjZ.x));
    unsigned q = (unsigned)(m * CN_SCALE + 0.5f);
    if (q) atomicAdd(&cn_u32[i], q);
}

__global__ __launch_bounds__(256)
void k_atom_weights_rec(const unsigned* __restrict__ cn_u32,
                        const int* __restrict__ numbers,
                        const float* __restrict__ ref_cn_table,
                        const float* __restrict__ r4r2,
                        __half* __restrict__ rec,
                        int n_atoms) {
    int a = blockIdx.x * blockDim.x + threadIdx.x;
    if (a >= n_atoms) return;
    float c = (float)cn_u32[a] * CN_INV;
    int Z = numbers[a];
    float w[5];
    float s = 0.0f;
#pragma unroll
    for (int r = 0; r < 5; ++r) {
        float rcn = ref_cn_table[Z * 5 + r];
        float d = rcn - c;
        float wv = (rcn >= 0.0f) ? expf(-WF_F * d * d) : 0.0f;
        w[r] = wv;
        s += wv;
    }
    float den = s + EPS_F;
    __half* rr = rec + (size_t)a * 8;
#pragma unroll
    for (int r = 0; r < 5; ++r) rr[r] = __float2half(w[r] / den);
    rr[5] = __float2half(r4r2[Z]);
    rr[6] = __float2half(0.0f);
    rr[7] = __float2half(0.0f);
}

// ---------------- energy ----------------
// 4 edges/thread, depth-1 gather chains, all loads issued upfront with
// static names (no runtime-indexed register arrays -> no scratch).
#define LOADC(p, z) do { \
    const uint4* _cp = reinterpret_cast<const uint4*>(c6h + (size_t)(z) * C6PADH); \
    p##0 = _cp[0]; p##1 = _cp[1]; p##2 = _cp[2]; p##3 = _cp[3]; } while (0)

template<bool STASH>
__global__ __launch_bounds__(256)
void k_energy(const float* __restrict__ dr_vec,
              const float* __restrict__ dr_stash,
              const int* __restrict__ idx_i,
              const int* __restrict__ idx_j,
              const unsigned short* __restrict__ zpair,
              const __half* __restrict__ rec,    // [N,8] halfs = 1 uint4
              const __half* __restrict__ c6h,    // [95*95][32] halfs
              double* __restrict__ e_acc,
              int n_edges) {
    double local = 0.0;
    const uint4* recv = reinterpret_cast<const uint4*>(rec);
    int nquad = (n_edges + 3) >> 2;
    int tid = blockIdx.x * blockDim.x + threadIdx.x;
    int stride = gridDim.x * blockDim.x;
    for (int qd = tid; qd < nquad; qd += stride) {
        int e0 = qd << 2;
        int ne = n_edges - e0;
        if (ne > 4) ne = 4;
        if (ne == 4) {
            int4 i4 = *reinterpret_cast<const int4*>(idx_i + e0);
            int4 j4 = *reinterpret_cast<const int4*>(idx_j + e0);
            uint2 z2 = *reinterpret_cast<const uint2*>(zpair + e0);
            int zp0 = (int)(z2.x & 0xFFFFu), zp1 = (int)(z2.x >> 16);
            int zp2 = (int)(z2.y & 0xFFFFu), zp3 = (int)(z2.y >> 16);
            float drq0, drq1, drq2, drq3;
            if (STASH) {
                float4 d4 = *reinterpret_cast<const float4*>(dr_stash + e0);
                drq0 = d4.x; drq1 = d4.y; drq2 = d4.z; drq3 = d4.w;
            } else {
                float4 v0 = *reinterpret_cast<const float4*>(dr_vec + 3 * e0);
                float4 v1 = *reinterpret_cast<const float4*>(dr_vec + 3 * e0 + 4);
                float4 v2 = *reinterpret_cast<const float4*>(dr_vec + 3 * e0 + 8);
                drq0 = sqrtf(v0.x*v0.x + v0.y*v0.y + v0.z*v0.z) / BOHR_F;
                drq1 = sqrtf(v0.w*v0.w + v1.x*v1.x + v1.y*v1.y) / BOHR_F;
                drq2 = sqrtf(v1.z*v1.z + v1.w*v1.w + v2.x*v2.x) / BOHR_F;
                drq3 = sqrtf(v2.y*v2.y + v2.z*v2.z + v2.w*v2.w) / BOHR_F;
            }
            // all 24 gathers issued before any use (independent addresses)
            uint4 Ri0 = recv[i4.x], Ri1 = recv[i4.y];
            uint4 Ri2 = recv[i4.z], Ri3 = recv[i4.w];
            uint4 Rj0 = recv[j4.x], Rj1 = recv[j4.y];
            uint4 Rj2 = recv[j4.z], Rj3 = recv[j4.w];
            uint4 a0, a1, a2, a3;   LOADC(a, zp0);
            uint4 b0, b1, b2, b3;   LOADC(b, zp1);
            uint4 c0, c1, c2, c3;   LOADC(c, zp2);
            uint4 d0, d1, d2, d3;   LOADC(d, zp3);
            local += (double)edge_e(drq0, Ri0, Rj0, a0, a1, a2, a3);
            local += (double)edge_e(drq1, Ri1, Rj1, b0, b1, b2, b3);
            local += (double)edge_e(drq2, Ri2, Rj2, c0, c1, c2, c3);
            local += (double)edge_e(drq3, Ri3, Rj3, d0, d1, d2, d3);
        } else {
            for (int k = 0; k < ne; ++k) {
                int e = e0 + k;
                float dr;
                if (STASH) dr = dr_stash[e];
                else {
                    float x = dr_vec[3*e], y = dr_vec[3*e+1], z = dr_vec[3*e+2];
                    dr = sqrtf(x*x + y*y + z*z) / BOHR_F;
                }
                int i = idx_i[e], j = idx_j[e];
                uint4 Ri = recv[i];
                uint4 Rj = recv[j];
                const uint4* cp = reinterpret_cast<const uint4*>(
                    c6h + (size_t)zpair[e] * C6PADH);
                local += (double)edge_e(dr, Ri, Rj, cp[0], cp[1], cp[2], cp[3]);
            }
        }
    }

    __shared__ double sdata[4];
    for (int off = 32; off > 0; off >>= 1)
        local += __shfl_down(local, off, 64);
    int lane = threadIdx.x & 63;
    int wid  = threadIdx.x >> 6;
    if (lane == 0) sdata[wid] = local;
    __syncthreads();
    if (threadIdx.x == 0) {
        double s = sdata[0] + sdata[1] + sdata[2] + sdata[3];
        atomicAdd(e_acc, s);
    }
}

__global__ void k_finalize(const double* __restrict__ e_acc,
                           float* __restrict__ out) {
    out[0] = (float)(e_acc[0] * HA_D);
}

static inline size_t a16(size_t x) { return (x + 15) & ~(size_t)15; }

extern "C" void kernel_launch(void* const* d_in, const int* in_sizes, int n_in,
                              void* d_out, int out_size, void* d_ws, size_t ws_size,
                              hipStream_t stream) {
    const float* dr_vec      = (const float*)d_in[0];
    const float* ref_cn_tab  = (const float*)d_in[1];
    const float* ref_c6_tab  = (const float*)d_in[2];
    const float* r4r2        = (const float*)d_in[3];
    const float* rcov        = (const float*)d_in[4];
    const int*   numbers     = (const int*)d_in[5];
    const int*   idx         = (const int*)d_in[6];

    int n_atoms = in_sizes[5];
    int n_edges = in_sizes[6] / 2;
    const int* idx_i = idx;
    const int* idx_j = idx + n_edges;

    const int BS = 256;
    int nb = (n_atoms + 511) >> 9;
    int c6tot = NELEM * NELEM * C6PADH;

    char* ws = (char*)d_ws;
    double* e_acc = (double*)ws;

    // common prefix: [e_acc 16][rec N*16B][c6h][rcovZ N*8]
    size_t off_rec = 16;
    size_t off_c6p = a16(off_rec + (size_t)n_atoms * 8 * 2);
    size_t off_rcZ = a16(off_c6p + (size_t)c6tot * 2);
    size_t off_var = a16(off_rcZ + (size_t)n_atoms * 8);

    // sort path: [packed2 E*4][zpair E*2][pairs E*4][ghist][tot][base][stash E*4]
    size_t off_packed = off_var;
    size_t off_zp     = a16(off_packed + (size_t)n_edges * 4);
    size_t off_pairs  = a16(off_zp + (size_t)n_edges * 2);
    size_t off_ghist  = a16(off_pairs + (size_t)n_edges * 4);
    size_t off_tot    = a16(off_ghist + (size_t)nb * NBLK * 4);
    size_t off_base   = a16(off_tot + (size_t)nb * 4);
    size_t off_stash  = a16(off_base + (size_t)(nb + 1) * 4);
    size_t need_sort       = off_stash;
    size_t need_sort_stash = off_stash + (size_t)n_edges * 4;

    // atomic path: [cn N*4][zpair E*2][stash E*4]
    size_t off_cn   = off_var;
    size_t off_zpa  = a16(off_cn + (size_t)n_atoms * 4);
    size_t off_st_a = a16(off_zpa + (size_t)n_edges * 2);
    size_t need_atomic_stash = off_st_a + (size_t)n_edges * 4;

    int nquad   = (n_edges + 3) >> 2;
    int grid_q  = (nquad + BS - 1) / BS;
    if (grid_q > 8192) grid_q = 8192;
    int grid_c6 = (c6tot + BS - 1) / BS;
    int grid_a  = (n_atoms + BS - 1) / BS;

    __half* rec   = (__half*)(ws + off_rec);
    __half* c6h   = (__half*)(ws + off_c6p);
    uint2*  rcovZ = (uint2*)(ws + off_rcZ);

    k_prep_c6<<<grid_c6, BS, 0, stream>>>(ref_c6_tab, c6h, c6tot);
    k_prep_atom<<<grid_a, BS, 0, stream>>>(numbers, rcov, rcovZ, n_atoms);

    if (n_atoms <= (1 << 17) && nb <= 256 && ws_size >= need_sort) {
        bool stash = (ws_size >= need_sort_stash);
        unsigned*       packed2 = (unsigned*)(ws + off_packed);
        unsigned short* zpair   = (unsigned short*)(ws + off_zp);
        unsigned*       pairs   = (unsigned*)(ws + off_pairs);
        unsigned*       ghist   = (unsigned*)(ws + off_ghist);
        unsigned*       totals  = (unsigned*)(ws + off_tot);
        unsigned*       base    = (unsigned*)(ws + off_base);
        float* dr_stash = stash ? (float*)(ws + off_stash) : nullptr;

        hipMemsetAsync(d_ws, 0, 16, stream);   // e_acc only

        if (stash)
            k_bin<true><<<NBLK, BSW, 0, stream>>>(dr_vec, idx_i, idx_j, rcovZ,
                packed2, zpair, ghist, dr_stash, n_edges, nb);
        else
            k_bin<false><<<NBLK, BSW, 0, stream>>>(dr_vec, idx_i, idx_j, rcovZ,
                packed2, zpair, ghist, nullptr, n_edges, nb);

        k_scan_bucket<<<nb, NBLK, 0, stream>>>(ghist, totals);
        k_scan_base<<<1, 256, 0, stream>>>(totals, base, nb);

        k_scatter<<<NBLK, BSW, 0, stream>>>(packed2, ghist, base, pairs,
                                            n_edges, nb);

        k_reduce_weights<<<nb, 512, 0, stream>>>(pairs, base, numbers,
            ref_cn_tab, r4r2, rec, n_atoms);

        if (stash)
            k_energy<true><<<grid_q, BS, 0, stream>>>(dr_vec, dr_stash, idx_i,
                idx_j, zpair, rec, c6h, e_acc, n_edges);
        else
            k_energy<false><<<grid_q, BS, 0, stream>>>(dr_vec, nullptr, idx_i,
                idx_j, zpair, rec, c6h, e_acc, n_edges);
    } else {
        bool stash = (ws_size >= need_atomic_stash);
        unsigned*       cn_u32 = (unsigned*)(ws + off_cn);
        unsigned short* zpair  = (unsigned short*)(ws + off_zpa);
        float* dr_stash = stash ? (float*)(ws + off_st_a) : nullptr;

        hipMemsetAsync(d_ws, 0, 16, stream);
        hipMemsetAsync(cn_u32, 0, (size_t)n_atoms * 4, stream);

        int grid_e = (n_edges + BS - 1) / BS;

        if (stash)
            k_edges_cn_atomic<true><<<grid_e, BS, 0, stream>>>(dr_vec, idx_i,
                idx_j, rcovZ, cn_u32, zpair, dr_stash, n_edges);
        else
            k_edges_cn_atomic<false><<<grid_e, BS, 0, stream>>>(dr_vec, idx_i,
                idx_j, rcovZ, cn_u32, zpair, nullptr, n_edges);

        k_atom_weights_rec<<<grid_a, BS, 0, stream>>>(cn_u32, numbers,
            ref_cn_tab, r4r2, rec, n_atoms);

        if (stash)
            k_energy<true><<<grid_q, BS, 0, stream>>>(dr_vec, dr_stash, idx_i,
                idx_j, zpair, rec, c6h, e_acc, n_edges);
        else
            k_energy<false><<<grid_q, BS, 0, stream>>>(dr_vec, nullptr, idx_i,
                idx_j, zpair, rec, c6h, e_acc, n_edges);
    }

    k_finalize<<<1, 1, 0, stream>>>(e_acc, (float*)d_out);
}